// Round 1
// baseline (2494.932 us; speedup 1.0000x reference)
//
#include <hip/hip_runtime.h>
#include <math.h>

#define NB 16
#define NH 16
#define SEQ 1024
#define DIM 1024
#define HD 64

// ---------------------------------------------------------------------------
// Kernel 1: y = x @ W^T + b, output written in (B, H, S, hd) layout.
// grid (DIM/128, (NB*SEQ)/128, 3), block 256.  blockIdx.z selects Q/K/V.
// 128x128 tile, 8x8 micro-tile, K-step 16, fp32 vector FMA.
// ---------------------------------------------------------------------------
__global__ __launch_bounds__(256) void proj_kernel(
    const float* __restrict__ x,
    const float* __restrict__ Wq, const float* __restrict__ bq,
    const float* __restrict__ Wk, const float* __restrict__ bk,
    const float* __restrict__ Wv, const float* __restrict__ bv,
    float* __restrict__ Qo, float* __restrict__ Ko, float* __restrict__ Vo)
{
    __shared__ float As[16][132];   // [k][m] transposed-on-store
    __shared__ float Bs[16][132];   // [k][n]

    const int t  = threadIdx.x;
    const int tx = t & 15;          // n micro group
    const int ty = t >> 4;          // m micro group
    const int n0 = blockIdx.x * 128;
    const int m0 = blockIdx.y * 128;

    const float* W; const float* bias; float* outp;
    if      (blockIdx.z == 0) { W = Wq; bias = bq; outp = Qo; }
    else if (blockIdx.z == 1) { W = Wk; bias = bk; outp = Ko; }
    else                      { W = Wv; bias = bv; outp = Vo; }

    float acc[8][8];
    #pragma unroll
    for (int i = 0; i < 8; i++)
        #pragma unroll
        for (int j = 0; j < 8; j++) acc[i][j] = 0.f;

    for (int k0 = 0; k0 < DIM; k0 += 16) {
        __syncthreads();
        // stage A (x) and B (W) tiles: 128 rows x 16 k each, transposed into LDS
        #pragma unroll
        for (int q = 0; q < 2; q++) {
            int f   = q * 256 + t;          // 0..511 float4 slots
            int row = f >> 2;               // 0..127
            int kc  = (f & 3) * 4;          // 0,4,8,12
            float4 va = *(const float4*)(x + (size_t)(m0 + row) * DIM + k0 + kc);
            As[kc + 0][row] = va.x; As[kc + 1][row] = va.y;
            As[kc + 2][row] = va.z; As[kc + 3][row] = va.w;
            float4 vb = *(const float4*)(W + (size_t)(n0 + row) * DIM + k0 + kc);
            Bs[kc + 0][row] = vb.x; Bs[kc + 1][row] = vb.y;
            Bs[kc + 2][row] = vb.z; Bs[kc + 3][row] = vb.w;
        }
        __syncthreads();
        #pragma unroll
        for (int kk = 0; kk < 16; kk++) {
            float a[8], b[8];
            *(float4*)&a[0] = *(const float4*)&As[kk][ty * 8];
            *(float4*)&a[4] = *(const float4*)&As[kk][ty * 8 + 4];
            *(float4*)&b[0] = *(const float4*)&Bs[kk][tx * 8];
            *(float4*)&b[4] = *(const float4*)&Bs[kk][tx * 8 + 4];
            #pragma unroll
            for (int i = 0; i < 8; i++)
                #pragma unroll
                for (int j = 0; j < 8; j++)
                    acc[i][j] = fmaf(a[i], b[j], acc[i][j]);
        }
    }

    // epilogue: add bias, store in (B,H,S,hd) layout
    float bn[8];
    *(float4*)&bn[0] = *(const float4*)(bias + n0 + tx * 8);
    *(float4*)&bn[4] = *(const float4*)(bias + n0 + tx * 8 + 4);

    const int nbase = n0 + tx * 8;
    const int hh = nbase >> 6;        // head (8-col group never crosses a head)
    const int dh = nbase & 63;
    #pragma unroll
    for (int i = 0; i < 8; i++) {
        int m  = m0 + ty * 8 + i;
        int bb = m >> 10;
        int ss = m & 1023;
        size_t base = (((size_t)(bb * NH + hh)) * SEQ + ss) * HD + dh;
        float4 o0, o1;
        o0.x = acc[i][0] + bn[0]; o0.y = acc[i][1] + bn[1];
        o0.z = acc[i][2] + bn[2]; o0.w = acc[i][3] + bn[3];
        o1.x = acc[i][4] + bn[4]; o1.y = acc[i][5] + bn[5];
        o1.z = acc[i][6] + bn[6]; o1.w = acc[i][7] + bn[7];
        *(float4*)(outp + base)     = o0;
        *(float4*)(outp + base + 4) = o1;
    }
}

// ---------------------------------------------------------------------------
// Kernel 2: flash attention with inline positional bias.
// grid (SEQ/64, NH, NB), block 256 (tx 0..15 = k/d cols, ty 0..15 = q rows).
// 64(q) x 64(k) tiles, 4x4 micro, online softmax; row reductions are in-wave
// shfl_xor over the 16-lane tx group.  P is transposed through the K buffer.
// ---------------------------------------------------------------------------
__global__ __launch_bounds__(256) void attn_kernel(
    const float* __restrict__ Q, const float* __restrict__ K,
    const float* __restrict__ V, const float* __restrict__ vels,
    float* __restrict__ out)
{
    __shared__ float Qt[64][68];    // [d][i]
    __shared__ float KtPt[64][68];  // [d][j] for K, recycled as [j][i] for P
    __shared__ float Vs[64][68];    // [j][d]

    const int t  = threadIdx.x;
    const int tx = t & 15;
    const int ty = t >> 4;
    const int q0 = blockIdx.x * 64;
    const int h  = blockIdx.y;
    const int b  = blockIdx.z;

    const float* Qp = Q + ((size_t)(b * NH + h) * SEQ) * HD;
    const float* Kp = K + ((size_t)(b * NH + h) * SEQ) * HD;
    const float* Vp = V + ((size_t)(b * NH + h) * SEQ) * HD;

    // load Q tile transposed: Qt[d][i]
    #pragma unroll
    for (int q = 0; q < 4; q++) {
        int f   = q * 256 + t;
        int row = f >> 4;            // 0..63 q row
        int dc  = (f & 15) * 4;      // 0..60
        float4 v = *(const float4*)(Qp + (size_t)(q0 + row) * HD + dc);
        Qt[dc + 0][row] = v.x; Qt[dc + 1][row] = v.y;
        Qt[dc + 2][row] = v.z; Qt[dc + 3][row] = v.w;
    }

    float m_i[4], l_i[4], O[4][4];
    #pragma unroll
    for (int i = 0; i < 4; i++) {
        m_i[i] = -1e30f; l_i[i] = 0.f;
        #pragma unroll
        for (int j = 0; j < 4; j++) O[i][j] = 0.f;
    }
    float vq[4];
    #pragma unroll
    for (int i = 0; i < 4; i++) vq[i] = vels[q0 + ty * 4 + i];

    for (int kt = 0; kt < SEQ; kt += 64) {
        __syncthreads();   // prev PV done (also covers initial Qt fill)
        // stage K (transposed) and V (row-major) tiles
        #pragma unroll
        for (int q = 0; q < 4; q++) {
            int f   = q * 256 + t;
            int row = f >> 4;
            int dc  = (f & 15) * 4;
            float4 kv = *(const float4*)(Kp + (size_t)(kt + row) * HD + dc);
            KtPt[dc + 0][row] = kv.x; KtPt[dc + 1][row] = kv.y;
            KtPt[dc + 2][row] = kv.z; KtPt[dc + 3][row] = kv.w;
            float4 vv = *(const float4*)(Vp + (size_t)(kt + row) * HD + dc);
            *(float4*)&Vs[row][dc] = vv;
        }
        __syncthreads();

        // scores: 4x4 micro over d
        float sc[4][4];
        #pragma unroll
        for (int i = 0; i < 4; i++)
            #pragma unroll
            for (int j = 0; j < 4; j++) sc[i][j] = 0.f;
        #pragma unroll 8
        for (int d = 0; d < 64; d++) {
            float4 qf = *(const float4*)&Qt[d][ty * 4];
            float4 kf = *(const float4*)&KtPt[d][tx * 4];
            float qa[4] = {qf.x, qf.y, qf.z, qf.w};
            float ka[4] = {kf.x, kf.y, kf.z, kf.w};
            #pragma unroll
            for (int i = 0; i < 4; i++)
                #pragma unroll
                for (int j = 0; j < 4; j++)
                    sc[i][j] = fmaf(qa[i], ka[j], sc[i][j]);
        }

        // positional bias + online softmax
        float ek[4]; int kpar[4];
        #pragma unroll
        for (int j = 0; j < 4; j++) {
            int kcol = kt + tx * 4 + j;
            ek[j]   = expf(-(float)(kcol >> 1) * 0.0078125f);  // exp(-p/128)
            kpar[j] = kcol & 1;
        }
        #pragma unroll
        for (int i = 0; i < 4; i++) {
            #pragma unroll
            for (int j = 0; j < 4; j++) {
                float ang  = vq[i] * ek[j];
                float bias = kpar[j] ? cosf(ang) : sinf(ang);
                sc[i][j] = sc[i][j] * 0.125f + bias;
            }
            // row max across the 16-lane tx group
            float mx = fmaxf(fmaxf(sc[i][0], sc[i][1]), fmaxf(sc[i][2], sc[i][3]));
            #pragma unroll
            for (int msk = 1; msk < 16; msk <<= 1)
                mx = fmaxf(mx, __shfl_xor(mx, msk));
            float m_new = fmaxf(m_i[i], mx);
            float rs = 0.f;
            #pragma unroll
            for (int j = 0; j < 4; j++) {
                sc[i][j] = expf(sc[i][j] - m_new);   // sc now holds P
                rs += sc[i][j];
            }
            #pragma unroll
            for (int msk = 1; msk < 16; msk <<= 1)
                rs += __shfl_xor(rs, msk);
            float fac = expf(m_i[i] - m_new);
            l_i[i] = l_i[i] * fac + rs;
            m_i[i] = m_new;
            #pragma unroll
            for (int j = 0; j < 4; j++) O[i][j] *= fac;
        }

        __syncthreads();   // all threads done reading K from KtPt
        // transpose P into the recycled buffer: KtPt[j][i]
        #pragma unroll
        for (int i = 0; i < 4; i++)
            #pragma unroll
            for (int j = 0; j < 4; j++)
                KtPt[tx * 4 + j][ty * 4 + i] = sc[i][j];
        __syncthreads();

        // PV: O[i][d] += sum_j P[i][j] * V[j][d]
        #pragma unroll 8
        for (int j = 0; j < 64; j++) {
            float4 pf = *(const float4*)&KtPt[j][ty * 4];
            float4 vf = *(const float4*)&Vs[j][tx * 4];
            float pa[4] = {pf.x, pf.y, pf.z, pf.w};
            float va[4] = {vf.x, vf.y, vf.z, vf.w};
            #pragma unroll
            for (int i = 0; i < 4; i++)
                #pragma unroll
                for (int jj = 0; jj < 4; jj++)
                    O[i][jj] = fmaf(pa[i], va[jj], O[i][jj]);
        }
    }

    // epilogue: normalize and store (B, S, D) with D = h*64 + d
    #pragma unroll
    for (int i = 0; i < 4; i++) {
        int   row = q0 + ty * 4 + i;
        float inv = 1.f / l_i[i];
        float4 o;
        o.x = O[i][0] * inv; o.y = O[i][1] * inv;
        o.z = O[i][2] * inv; o.w = O[i][3] * inv;
        *(float4*)(out + ((size_t)(b * SEQ + row)) * DIM + h * HD + tx * 4) = o;
    }
}

extern "C" void kernel_launch(void* const* d_in, const int* in_sizes, int n_in,
                              void* d_out, int out_size, void* d_ws, size_t ws_size,
                              hipStream_t stream) {
    (void)in_sizes; (void)n_in; (void)out_size; (void)ws_size;
    const float* x    = (const float*)d_in[0];
    const float* vels = (const float*)d_in[1];
    const float* Wq   = (const float*)d_in[2];
    const float* bq   = (const float*)d_in[3];
    const float* Wk   = (const float*)d_in[4];
    const float* bk   = (const float*)d_in[5];
    const float* Wv   = (const float*)d_in[6];
    const float* bv   = (const float*)d_in[7];
    float* out = (float*)d_out;

    const size_t tsz = (size_t)NB * NH * SEQ * HD;   // 16.7M floats = 64 MB
    float* Qd = (float*)d_ws;
    float* Kd = Qd + tsz;
    float* Vd = Kd + tsz;

    dim3 pgrid(DIM / 128, (NB * SEQ) / 128, 3);
    proj_kernel<<<pgrid, 256, 0, stream>>>(x, Wq, bq, Wk, bk, Wv, bv, Qd, Kd, Vd);

    dim3 agrid(SEQ / 64, NH, NB);
    attn_kernel<<<agrid, 256, 0, stream>>>(Qd, Kd, Vd, vels, out);
}

// Round 3
// 1627.095 us; speedup vs baseline: 1.5334x; 1.5334x over previous
//
#include <hip/hip_runtime.h>
#include <math.h>

#define NB 16
#define NH 16
#define SEQ 1024
#define DIM 1024
#define HD 64

typedef _Float16 half8 __attribute__((ext_vector_type(8)));
typedef float floatx16 __attribute__((ext_vector_type(16)));

// ---------------------------------------------------------------------------
// Kernel 0: transposed positional-bias table biasT[k][q] (f32, S x S).
// log10(1e4)=4 -> div_term[j] = exp(-j/128).
// ---------------------------------------------------------------------------
__global__ void bias_kernel(const float* __restrict__ vels, float* __restrict__ biasT)
{
    int q = blockIdx.x * 256 + threadIdx.x;   // 0..1023
    int k = blockIdx.y;                       // 0..1023
    float ek  = expf(-(float)(k >> 1) * 0.0078125f);
    float ang = vels[q] * ek;
    biasT[(size_t)k * SEQ + q] = (k & 1) ? cosf(ang) : sinf(ang);
}

// ---------------------------------------------------------------------------
// Kernel 1: y = x @ W^T + b (fp32 VALU).  Epilogue emits f16:
// z=0 -> Qh/Ql (hi/lo split), z=1 -> Kh/Kl, z=2 -> Vt in (B,H,d,s) layout.
// ---------------------------------------------------------------------------
__global__ __launch_bounds__(256) void proj_kernel(
    const float* __restrict__ x,
    const float* __restrict__ Wq, const float* __restrict__ bq,
    const float* __restrict__ Wk, const float* __restrict__ bk,
    const float* __restrict__ Wv, const float* __restrict__ bv,
    _Float16* __restrict__ Qh, _Float16* __restrict__ Ql,
    _Float16* __restrict__ Kh, _Float16* __restrict__ Kl,
    _Float16* __restrict__ Vt)
{
    __shared__ float As[16][132];   // [k][m]
    __shared__ float Bs[16][132];   // [k][n]

    const int t  = threadIdx.x;
    const int tx = t & 15;
    const int ty = t >> 4;
    const int n0 = blockIdx.x * 128;
    const int m0 = blockIdx.y * 128;

    const float* W; const float* bias;
    if      (blockIdx.z == 0) { W = Wq; bias = bq; }
    else if (blockIdx.z == 1) { W = Wk; bias = bk; }
    else                      { W = Wv; bias = bv; }

    float acc[8][8];
    #pragma unroll
    for (int i = 0; i < 8; i++)
        #pragma unroll
        for (int j = 0; j < 8; j++) acc[i][j] = 0.f;

    for (int k0 = 0; k0 < DIM; k0 += 16) {
        __syncthreads();
        #pragma unroll
        for (int q = 0; q < 2; q++) {
            int f   = q * 256 + t;
            int row = f >> 2;
            int kc  = (f & 3) * 4;
            float4 va = *(const float4*)(x + (size_t)(m0 + row) * DIM + k0 + kc);
            As[kc + 0][row] = va.x; As[kc + 1][row] = va.y;
            As[kc + 2][row] = va.z; As[kc + 3][row] = va.w;
            float4 vb = *(const float4*)(W + (size_t)(n0 + row) * DIM + k0 + kc);
            Bs[kc + 0][row] = vb.x; Bs[kc + 1][row] = vb.y;
            Bs[kc + 2][row] = vb.z; Bs[kc + 3][row] = vb.w;
        }
        __syncthreads();
        #pragma unroll
        for (int kk = 0; kk < 16; kk++) {
            float a[8], b[8];
            *(float4*)&a[0] = *(const float4*)&As[kk][ty * 8];
            *(float4*)&a[4] = *(const float4*)&As[kk][ty * 8 + 4];
            *(float4*)&b[0] = *(const float4*)&Bs[kk][tx * 8];
            *(float4*)&b[4] = *(const float4*)&Bs[kk][tx * 8 + 4];
            #pragma unroll
            for (int i = 0; i < 8; i++)
                #pragma unroll
                for (int j = 0; j < 8; j++)
                    acc[i][j] = fmaf(a[i], b[j], acc[i][j]);
        }
    }

    float bn[8];
    *(float4*)&bn[0] = *(const float4*)(bias + n0 + tx * 8);
    *(float4*)&bn[4] = *(const float4*)(bias + n0 + tx * 8 + 4);

    const int nbase = n0 + tx * 8;
    const int hh = nbase >> 6;
    const int dh = nbase & 63;
    const int m  = m0 + ty * 8;
    const int bb = m >> 10;          // 128-row tile never crosses a batch
    const int s0 = m & 1023;

    if (blockIdx.z < 2) {
        _Float16* H = (blockIdx.z == 0) ? Qh : Kh;
        _Float16* L = (blockIdx.z == 0) ? Ql : Kl;
        #pragma unroll
        for (int i = 0; i < 8; i++) {
            union { _Float16 h[8]; uint4 u; } Hv, Lv;
            #pragma unroll
            for (int j = 0; j < 8; j++) {
                float v = acc[i][j] + bn[j];
                _Float16 hi = (_Float16)v;
                Hv.h[j] = hi;
                Lv.h[j] = (_Float16)(v - (float)hi);
            }
            size_t base = (((size_t)(bb * NH + hh)) * SEQ + (s0 + i)) * HD + dh;
            *(uint4*)(H + base) = Hv.u;
            *(uint4*)(L + base) = Lv.u;
        }
    } else {
        #pragma unroll
        for (int j = 0; j < 8; j++) {
            union { _Float16 h[8]; uint4 u; } P8;
            #pragma unroll
            for (int i = 0; i < 8; i++) P8.h[i] = (_Float16)(acc[i][j] + bn[j]);
            *(uint4*)(Vt + ((size_t)(bb * NH + hh) * HD + dh + j) * SEQ + s0) = P8.u;
        }
    }
}

// ---------------------------------------------------------------------------
// Kernel 2: flash attention, 32x32x16 f16 MFMA, swapped operands.
//   QK^T: D[k][q] = mfma(A=K, B=Q)      (split-f16: KhQh + KhQl + KlQh)
//   PV:   O^T[d][q] = mfma(A=Vt, B=P)
// Lane pair (ln, ln+32) jointly owns one q-row: the row's 64 k-scores are
// split across the pair (C/D row map), so row max/sum need ONE xor-32
// shuffle each (the round-2 bug: these were missing).
// ---------------------------------------------------------------------------
__global__ __launch_bounds__(256) void attn_mfma(
    const _Float16* __restrict__ Qh, const _Float16* __restrict__ Ql,
    const _Float16* __restrict__ Kh, const _Float16* __restrict__ Kl,
    const _Float16* __restrict__ Vt, const float* __restrict__ biasT,
    float* __restrict__ out)
{
    __shared__ __align__(16) char lds[40960];
    char* KsH = lds;                 // 8 KB: K hi tile [64 kcol][64 d] swz
    char* KsL = lds + 8192;          // 8 KB: K lo tile
    char* Vts = lds + 16384;         // 8 KB: Vt tile [64 d][64 s] swz
    // P per-wave: lds + 24576 + w*4096  ([32 q][64 k] f16 swz)

    const int t    = threadIdx.x;
    const int lane = t & 63;
    const int w    = t >> 6;
    const int g    = lane >> 5;      // 0/1
    const int ln   = lane & 31;
    const int q0   = blockIdx.x * 128;
    const int h = blockIdx.y, b = blockIdx.z;
    const size_t bh = (size_t)b * NH + h;

    const _Float16* Qhp = Qh + bh * (SEQ * HD);
    const _Float16* Qlp = Ql + bh * (SEQ * HD);
    const _Float16* Khp = Kh + bh * (SEQ * HD);
    const _Float16* Klp = Kl + bh * (SEQ * HD);
    const _Float16* Vtp = Vt + bh * (HD * SEQ);
    char* Pw = lds + 24576 + w * 4096;

    // Q fragments (B operand), hoisted: lane's own q-row.
    const int qr = q0 + w * 32 + ln;
    half8 qf[2][4];
    #pragma unroll
    for (int ks = 0; ks < 4; ks++) {
        qf[0][ks] = *(const half8*)(Qhp + (size_t)qr * HD + ks * 16 + g * 8);
        qf[1][ks] = *(const half8*)(Qlp + (size_t)qr * HD + ks * 16 + g * 8);
    }

    floatx16 O[2];
    #pragma unroll
    for (int mt = 0; mt < 2; mt++)
        #pragma unroll
        for (int r = 0; r < 16; r++) O[mt][r] = 0.f;
    float m_i = -1e30f, l_i = 0.f;

    for (int kt = 0; kt < SEQ; kt += 64) {
        __syncthreads();             // previous tile's LDS reads done
        #pragma unroll
        for (int c = 0; c < 2; c++) {
            int id = c * 256 + t;
            int r  = id >> 3;                // tile row
            int cb = (id & 7) << 4;          // byte col (16B chunks)
            int wr = r * 128 + (cb ^ ((r & 7) << 4));
            *(uint4*)(KsH + wr) = *(const uint4*)((const char*)(Khp + (size_t)(kt + r) * HD) + cb);
            *(uint4*)(KsL + wr) = *(const uint4*)((const char*)(Klp + (size_t)(kt + r) * HD) + cb);
            *(uint4*)(Vts + wr) = *(const uint4*)((const char*)(Vtp + (size_t)r * SEQ + kt) + cb);
        }
        __syncthreads();

        // ---- QK^T (swapped): acc[mt] = D[k = mt*32 + rowmap][q = ln]
        float sc[2][16];
        #pragma unroll
        for (int mt = 0; mt < 2; mt++) {
            floatx16 acc;
            #pragma unroll
            for (int r = 0; r < 16; r++) acc[r] = 0.f;
            #pragma unroll
            for (int ks = 0; ks < 4; ks++) {
                int row = mt * 32 + ln;
                int ad  = row * 128 + ((ks * 32 + g * 16) ^ ((row & 7) << 4));
                half8 kh = *(const half8*)(KsH + ad);
                half8 kl = *(const half8*)(KsL + ad);
                acc = __builtin_amdgcn_mfma_f32_32x32x16_f16(kh, qf[0][ks], acc, 0, 0, 0);
                acc = __builtin_amdgcn_mfma_f32_32x32x16_f16(kh, qf[1][ks], acc, 0, 0, 0);
                acc = __builtin_amdgcn_mfma_f32_32x32x16_f16(kl, qf[0][ks], acc, 0, 0, 0);
            }
            #pragma unroll
            for (int r = 0; r < 16; r++) sc[mt][r] = acc[r];
        }

        // ---- bias + online softmax.  The q-row's 64 scores live in the
        //      lane pair (ln, ln+32): reduce max/sum across the pair.
        const float* bT = biasT + (size_t)kt * SEQ + q0 + w * 32 + ln;
        float mx = m_i;
        #pragma unroll
        for (int mt = 0; mt < 2; mt++)
            #pragma unroll
            for (int r = 0; r < 16; r++) {
                int kc = (r & 3) + ((r >> 2) << 3) + (g << 2) + (mt << 5);
                float v = fmaf(sc[mt][r], 0.125f, bT[(size_t)kc * SEQ]);
                sc[mt][r] = v;
                mx = fmaxf(mx, v);
            }
        mx = fmaxf(mx, __shfl_xor(mx, 32));          // FIX: join lane halves
        float fac = __expf(m_i - mx);
        m_i = mx;
        float rs = 0.f;
        #pragma unroll
        for (int mt = 0; mt < 2; mt++)
            #pragma unroll
            for (int rb = 0; rb < 4; rb++) {
                float p0 = __expf(sc[mt][rb * 4 + 0] - mx);
                float p1 = __expf(sc[mt][rb * 4 + 1] - mx);
                float p2 = __expf(sc[mt][rb * 4 + 2] - mx);
                float p3 = __expf(sc[mt][rb * 4 + 3] - mx);
                rs += (p0 + p1) + (p2 + p3);
                union { _Float16 hv[4]; uint2 u2; } pk;
                pk.hv[0] = (_Float16)p0; pk.hv[1] = (_Float16)p1;
                pk.hv[2] = (_Float16)p2; pk.hv[3] = (_Float16)p3;
                // 4 consecutive k per chunk: k0 = rb*8 + g*4 + mt*32
                int cbb = (((rb << 4) + (g << 3) + (mt << 6)) ^ ((ln & 7) << 4));
                *(uint2*)(Pw + ln * 128 + cbb) = pk.u2;
            }
        rs += __shfl_xor(rs, 32);                    // FIX: join lane halves
        l_i = l_i * fac + rs;

        // ---- PV (swapped): O^T[d][q] += mfma(A=Vt, B=P)
        #pragma unroll
        for (int mt = 0; mt < 2; mt++) {
            floatx16 o = O[mt];
            #pragma unroll
            for (int r = 0; r < 16; r++) o[r] *= fac;
            #pragma unroll
            for (int ks = 0; ks < 4; ks++) {
                int row = mt * 32 + ln;     // d row
                int ad  = row * 128 + ((ks * 32 + g * 16) ^ ((row & 7) << 4));
                half8 vf = *(const half8*)(Vts + ad);
                half8 pf = *(const half8*)(Pw + ln * 128 + ((ks * 32 + g * 16) ^ ((ln & 7) << 4)));
                o = __builtin_amdgcn_mfma_f32_32x32x16_f16(vf, pf, o, 0, 0, 0);
            }
            O[mt] = o;
        }
    }

    // ---- epilogue: O^T -> LDS transpose -> coalesced f32 stores
    __syncthreads();                 // all waves done with K/V/P regions
    float inv = 1.f / l_i;
    float* Ot = (float*)lds + w * (64 * 33);   // 8448 B per wave, padded rows
    #pragma unroll
    for (int mt = 0; mt < 2; mt++)
        #pragma unroll
        for (int r = 0; r < 16; r++) {
            int d = (r & 3) + ((r >> 2) << 3) + (g << 2) + (mt << 5);
            Ot[d * 33 + ln] = O[mt][r] * inv;
        }
    #pragma unroll
    for (int ps = 0; ps < 8; ps++) {
        int qrow = ps * 4 + (lane >> 4);
        int dc   = (lane & 15) * 4;
        float4 o;
        o.x = Ot[(dc + 0) * 33 + qrow];
        o.y = Ot[(dc + 1) * 33 + qrow];
        o.z = Ot[(dc + 2) * 33 + qrow];
        o.w = Ot[(dc + 3) * 33 + qrow];
        *(float4*)(out + ((size_t)b * SEQ + q0 + w * 32 + qrow) * DIM + h * HD + dc) = o;
    }
}

extern "C" void kernel_launch(void* const* d_in, const int* in_sizes, int n_in,
                              void* d_out, int out_size, void* d_ws, size_t ws_size,
                              hipStream_t stream) {
    (void)in_sizes; (void)n_in; (void)out_size; (void)ws_size;
    const float* x    = (const float*)d_in[0];
    const float* vels = (const float*)d_in[1];
    const float* Wq   = (const float*)d_in[2];
    const float* bq   = (const float*)d_in[3];
    const float* Wk   = (const float*)d_in[4];
    const float* bk   = (const float*)d_in[5];
    const float* Wv   = (const float*)d_in[6];
    const float* bv   = (const float*)d_in[7];
    float* out = (float*)d_out;

    // workspace layout (bytes): biasT 4MB | Qh Ql Kh Kl Vt 32MB each = 164MB
    char* ws = (char*)d_ws;
    float*     biasT = (float*)ws;
    _Float16*  Qhp = (_Float16*)(ws + (4u << 20));
    _Float16*  Qlp = (_Float16*)(ws + (36u << 20));
    _Float16*  Khp = (_Float16*)(ws + (68u << 20));
    _Float16*  Klp = (_Float16*)(ws + (100u << 20));
    _Float16*  Vtp = (_Float16*)(ws + (132u << 20));

    bias_kernel<<<dim3(SEQ / 256, SEQ), 256, 0, stream>>>(vels, biasT);

    dim3 pgrid(DIM / 128, (NB * SEQ) / 128, 3);
    proj_kernel<<<pgrid, 256, 0, stream>>>(x, Wq, bq, Wk, bk, Wv, bv,
                                           Qhp, Qlp, Khp, Klp, Vtp);

    dim3 agrid(SEQ / 128, NH, NB);
    attn_mfma<<<agrid, 256, 0, stream>>>(Qhp, Qlp, Khp, Klp, Vtp, biasT, out);
}

// Round 4
// 679.117 us; speedup vs baseline: 3.6738x; 2.3959x over previous
//
#include <hip/hip_runtime.h>
#include <math.h>

#define NB 16
#define NH 16
#define SEQ 1024
#define DIM 1024
#define HD 64

typedef _Float16 half8 __attribute__((ext_vector_type(8)));
typedef float floatx16 __attribute__((ext_vector_type(16)));

// ---------------------------------------------------------------------------
// Kernel 0a: W -> f16 hi/lo split.  WH/WL hold Wq,Wk,Wv contiguously.
// ---------------------------------------------------------------------------
__global__ __launch_bounds__(256) void convw_kernel(
    const float* __restrict__ Wq, const float* __restrict__ Wk,
    const float* __restrict__ Wv,
    _Float16* __restrict__ WH, _Float16* __restrict__ WL)
{
    int i = (blockIdx.x * 256 + threadIdx.x) * 4;
    const float* src = (blockIdx.y == 0) ? Wq : (blockIdx.y == 1) ? Wk : Wv;
    float4 v = *(const float4*)(src + i);
    float vv[4] = {v.x, v.y, v.z, v.w};
    union { _Float16 h[4]; uint2 u; } Hh, Ll;
    #pragma unroll
    for (int j = 0; j < 4; j++) {
        _Float16 hi = (_Float16)vv[j];
        Hh.h[j] = hi;
        Ll.h[j] = (_Float16)(vv[j] - (float)hi);
    }
    size_t off = (size_t)blockIdx.y * (DIM * DIM) + i;
    *(uint2*)(WH + off) = Hh.u;
    *(uint2*)(WL + off) = Ll.u;
}

// ---------------------------------------------------------------------------
// Kernel 0b: transposed positional-bias table biasT[k][q] (f32, S x S).
// log10(1e4)=4 -> div_term[j] = exp(-j/128).
// ---------------------------------------------------------------------------
__global__ void bias_kernel(const float* __restrict__ vels, float* __restrict__ biasT)
{
    int q = blockIdx.x * 256 + threadIdx.x;   // 0..1023
    int k = blockIdx.y;                       // 0..1023
    float ek  = expf(-(float)(k >> 1) * 0.0078125f);
    float ang = vels[q] * ek;
    biasT[(size_t)k * SEQ + q] = (k & 1) ? cosf(ang) : sinf(ang);
}

// ---------------------------------------------------------------------------
// Kernel 1: projections via 32x32x16 f16 MFMA.
// y = x @ W^T + b.  x converted f32->f16 during staging; W pre-split hi/lo
// (q = xh*Wh + xh*Wl: only x-rounding error survives).  V: single-term.
// 128x128 tile, BK=32, 4 waves (64x64 each), swizzled LDS, XCD-chunked grid.
// z=0 -> Qh/Ql, z=1 -> Kh/Kl (hi/lo of the f32 accumulator), z=2 -> Vt
// in (B,H,d,s) transposed layout.
// ---------------------------------------------------------------------------
__global__ __launch_bounds__(256) void proj_mfma(
    const float* __restrict__ x,
    const _Float16* __restrict__ WH, const _Float16* __restrict__ WL,
    const float* __restrict__ bq, const float* __restrict__ bk,
    const float* __restrict__ bvp,
    _Float16* __restrict__ Qh, _Float16* __restrict__ Ql,
    _Float16* __restrict__ Kh, _Float16* __restrict__ Kl,
    _Float16* __restrict__ Vt)
{
    __shared__ __align__(16) char lds[24576];
    char* Xs  = lds;            // [128][32] f16, swizzled, 8 KB
    char* WhS = lds + 8192;
    char* WlS = lds + 16384;

    const int t    = threadIdx.x;
    const int lane = t & 63;
    const int w    = t >> 6;
    const int g    = lane >> 5;
    const int ln   = lane & 31;
    const int wm   = w >> 1, wn = w & 1;

    // XCD-chunked swizzle: 3072 blocks = 8 XCDs x 384; consecutive sw share
    // the same x panel (nx fastest) on one XCD's L2.
    int hw  = blockIdx.x;
    int sw  = (hw & 7) * 384 + (hw >> 3);
    int z   = sw >> 10;
    int rem = sw & 1023;
    const int m0 = (rem >> 3) * 128;
    const int n0 = (rem & 7) * 128;
    const bool isV = (z == 2);

    const _Float16* Whp = WH + (size_t)z * (DIM * DIM);
    const _Float16* Wlp = WL + (size_t)z * (DIM * DIM);
    const float* bias = (z == 0) ? bq : (z == 1) ? bk : bvp;

    floatx16 acc[4];
    #pragma unroll
    for (int i = 0; i < 4; i++)
        #pragma unroll
        for (int r = 0; r < 16; r++) acc[i][r] = 0.f;

    for (int k0 = 0; k0 < DIM; k0 += 32) {
        __syncthreads();
        // ---- stage x tile (f32 -> f16) : 128 rows x 32 k
        #pragma unroll
        for (int i = 0; i < 4; i++) {
            int c   = i * 256 + t;       // 0..1023 float4 chunks
            int row = c >> 3;
            int k4  = c & 7;
            float4 xv = *(const float4*)(x + (size_t)(m0 + row) * DIM + k0 + k4 * 4);
            union { _Float16 h[4]; uint2 u; } cv;
            cv.h[0] = (_Float16)xv.x; cv.h[1] = (_Float16)xv.y;
            cv.h[2] = (_Float16)xv.z; cv.h[3] = (_Float16)xv.w;
            int bo = row * 64 + (((k4 >> 1) << 4) ^ ((row & 3) << 4)) + (k4 & 1) * 8;
            *(uint2*)(Xs + bo) = cv.u;
        }
        // ---- stage W hi (and lo for Q/K) : 128 rows x 32 k, f16 direct
        #pragma unroll
        for (int i = 0; i < 2; i++) {
            int c   = i * 256 + t;       // 0..511 uint4 chunks
            int row = c >> 2;
            int c16 = c & 3;
            int bo  = row * 64 + ((c16 << 4) ^ ((row & 3) << 4));
            size_t ga = (size_t)(n0 + row) * DIM + k0 + c16 * 8;
            *(uint4*)(WhS + bo) = *(const uint4*)(Whp + ga);
            if (!isV) *(uint4*)(WlS + bo) = *(const uint4*)(Wlp + ga);
        }
        __syncthreads();

        #pragma unroll
        for (int ksub = 0; ksub < 2; ksub++) {
            half8 xa[2], wh[2];
            #pragma unroll
            for (int mt = 0; mt < 2; mt++) {
                int row = wm * 64 + mt * 32 + ln;
                xa[mt] = *(const half8*)(Xs + row * 64 +
                          ((((ksub * 2 + g) << 4) ^ ((row & 3) << 4))));
            }
            #pragma unroll
            for (int nt = 0; nt < 2; nt++) {
                int row = wn * 64 + nt * 32 + ln;
                wh[nt] = *(const half8*)(WhS + row * 64 +
                          ((((ksub * 2 + g) << 4) ^ ((row & 3) << 4))));
            }
            if (!isV) {
                half8 wl[2];
                #pragma unroll
                for (int nt = 0; nt < 2; nt++) {
                    int row = wn * 64 + nt * 32 + ln;
                    wl[nt] = *(const half8*)(WlS + row * 64 +
                              ((((ksub * 2 + g) << 4) ^ ((row & 3) << 4))));
                }
                #pragma unroll
                for (int mt = 0; mt < 2; mt++)
                    #pragma unroll
                    for (int nt = 0; nt < 2; nt++) {
                        acc[mt * 2 + nt] = __builtin_amdgcn_mfma_f32_32x32x16_f16(
                            xa[mt], wh[nt], acc[mt * 2 + nt], 0, 0, 0);
                        acc[mt * 2 + nt] = __builtin_amdgcn_mfma_f32_32x32x16_f16(
                            xa[mt], wl[nt], acc[mt * 2 + nt], 0, 0, 0);
                    }
            } else {
                // V swapped: D[n][m=ln] so Vt stores are s-contiguous
                #pragma unroll
                for (int nt = 0; nt < 2; nt++)
                    #pragma unroll
                    for (int mt = 0; mt < 2; mt++)
                        acc[nt * 2 + mt] = __builtin_amdgcn_mfma_f32_32x32x16_f16(
                            wh[nt], xa[mt], acc[nt * 2 + mt], 0, 0, 0);
            }
        }
    }

    // ---- epilogue
    if (!isV) {
        _Float16* H = (z == 0) ? Qh : Kh;
        _Float16* L = (z == 0) ? Ql : Kl;
        float bnv[2];
        #pragma unroll
        for (int nt = 0; nt < 2; nt++) bnv[nt] = bias[n0 + wn * 64 + nt * 32 + ln];
        #pragma unroll
        for (int mt = 0; mt < 2; mt++)
            #pragma unroll
            for (int nt = 0; nt < 2; nt++) {
                int n = n0 + wn * 64 + nt * 32 + ln;
                int hh = n >> 6, dh = n & 63;
                #pragma unroll
                for (int r = 0; r < 16; r++) {
                    int m = m0 + wm * 64 + mt * 32 + (r & 3) + ((r >> 2) << 3) + (g << 2);
                    float v = acc[mt * 2 + nt][r] + bnv[nt];
                    _Float16 hi = (_Float16)v;
                    _Float16 lo = (_Float16)(v - (float)hi);
                    size_t base = (((size_t)((m >> 10) * NH + hh)) * SEQ + (m & 1023)) * HD + dh;
                    H[base] = hi;
                    L[base] = lo;
                }
            }
    } else {
        #pragma unroll
        for (int nt = 0; nt < 2; nt++)
            #pragma unroll
            for (int mt = 0; mt < 2; mt++) {
                int m  = m0 + wm * 64 + mt * 32 + ln;
                int bb = m >> 10, s = m & 1023;
                #pragma unroll
                for (int r = 0; r < 16; r++) {
                    int n = n0 + wn * 64 + nt * 32 + (r & 3) + ((r >> 2) << 3) + (g << 2);
                    float v = acc[nt * 2 + mt][r] + bias[n];
                    Vt[(((size_t)(bb * NH + (n >> 6))) * HD + (n & 63)) * SEQ + s] = (_Float16)v;
                }
            }
    }
}

// ---------------------------------------------------------------------------
// Kernel 2: flash attention, 32x32x16 f16 MFMA, swapped operands (unchanged
// from round 3, which passed at absmax 3.9e-3).
// ---------------------------------------------------------------------------
__global__ __launch_bounds__(256) void attn_mfma(
    const _Float16* __restrict__ Qh, const _Float16* __restrict__ Ql,
    const _Float16* __restrict__ Kh, const _Float16* __restrict__ Kl,
    const _Float16* __restrict__ Vt, const float* __restrict__ biasT,
    float* __restrict__ out)
{
    __shared__ __align__(16) char lds[40960];
    char* KsH = lds;                 // 8 KB: K hi tile [64 kcol][64 d] swz
    char* KsL = lds + 8192;          // 8 KB: K lo tile
    char* Vts = lds + 16384;         // 8 KB: Vt tile [64 d][64 s] swz
    // P per-wave: lds + 24576 + w*4096

    const int t    = threadIdx.x;
    const int lane = t & 63;
    const int w    = t >> 6;
    const int g    = lane >> 5;
    const int ln   = lane & 31;
    const int q0   = blockIdx.x * 128;
    const int h = blockIdx.y, b = blockIdx.z;
    const size_t bh = (size_t)b * NH + h;

    const _Float16* Qhp = Qh + bh * (SEQ * HD);
    const _Float16* Qlp = Ql + bh * (SEQ * HD);
    const _Float16* Khp = Kh + bh * (SEQ * HD);
    const _Float16* Klp = Kl + bh * (SEQ * HD);
    const _Float16* Vtp = Vt + bh * (HD * SEQ);
    char* Pw = lds + 24576 + w * 4096;

    const int qr = q0 + w * 32 + ln;
    half8 qf[2][4];
    #pragma unroll
    for (int ks = 0; ks < 4; ks++) {
        qf[0][ks] = *(const half8*)(Qhp + (size_t)qr * HD + ks * 16 + g * 8);
        qf[1][ks] = *(const half8*)(Qlp + (size_t)qr * HD + ks * 16 + g * 8);
    }

    floatx16 O[2];
    #pragma unroll
    for (int mt = 0; mt < 2; mt++)
        #pragma unroll
        for (int r = 0; r < 16; r++) O[mt][r] = 0.f;
    float m_i = -1e30f, l_i = 0.f;

    for (int kt = 0; kt < SEQ; kt += 64) {
        __syncthreads();
        #pragma unroll
        for (int c = 0; c < 2; c++) {
            int id = c * 256 + t;
            int r  = id >> 3;
            int cb = (id & 7) << 4;
            int wr = r * 128 + (cb ^ ((r & 7) << 4));
            *(uint4*)(KsH + wr) = *(const uint4*)((const char*)(Khp + (size_t)(kt + r) * HD) + cb);
            *(uint4*)(KsL + wr) = *(const uint4*)((const char*)(Klp + (size_t)(kt + r) * HD) + cb);
            *(uint4*)(Vts + wr) = *(const uint4*)((const char*)(Vtp + (size_t)r * SEQ + kt) + cb);
        }
        __syncthreads();

        float sc[2][16];
        #pragma unroll
        for (int mt = 0; mt < 2; mt++) {
            floatx16 acc;
            #pragma unroll
            for (int r = 0; r < 16; r++) acc[r] = 0.f;
            #pragma unroll
            for (int ks = 0; ks < 4; ks++) {
                int row = mt * 32 + ln;
                int ad  = row * 128 + ((ks * 32 + g * 16) ^ ((row & 7) << 4));
                half8 kh = *(const half8*)(KsH + ad);
                half8 kl = *(const half8*)(KsL + ad);
                acc = __builtin_amdgcn_mfma_f32_32x32x16_f16(kh, qf[0][ks], acc, 0, 0, 0);
                acc = __builtin_amdgcn_mfma_f32_32x32x16_f16(kh, qf[1][ks], acc, 0, 0, 0);
                acc = __builtin_amdgcn_mfma_f32_32x32x16_f16(kl, qf[0][ks], acc, 0, 0, 0);
            }
            #pragma unroll
            for (int r = 0; r < 16; r++) sc[mt][r] = acc[r];
        }

        const float* bT = biasT + (size_t)kt * SEQ + q0 + w * 32 + ln;
        float mx = m_i;
        #pragma unroll
        for (int mt = 0; mt < 2; mt++)
            #pragma unroll
            for (int r = 0; r < 16; r++) {
                int kc = (r & 3) + ((r >> 2) << 3) + (g << 2) + (mt << 5);
                float v = fmaf(sc[mt][r], 0.125f, bT[(size_t)kc * SEQ]);
                sc[mt][r] = v;
                mx = fmaxf(mx, v);
            }
        mx = fmaxf(mx, __shfl_xor(mx, 32));
        float fac = __expf(m_i - mx);
        m_i = mx;
        float rs = 0.f;
        #pragma unroll
        for (int mt = 0; mt < 2; mt++)
            #pragma unroll
            for (int rb = 0; rb < 4; rb++) {
                float p0 = __expf(sc[mt][rb * 4 + 0] - mx);
                float p1 = __expf(sc[mt][rb * 4 + 1] - mx);
                float p2 = __expf(sc[mt][rb * 4 + 2] - mx);
                float p3 = __expf(sc[mt][rb * 4 + 3] - mx);
                rs += (p0 + p1) + (p2 + p3);
                union { _Float16 hv[4]; uint2 u2; } pk;
                pk.hv[0] = (_Float16)p0; pk.hv[1] = (_Float16)p1;
                pk.hv[2] = (_Float16)p2; pk.hv[3] = (_Float16)p3;
                int cbb = (((rb << 4) + (g << 3) + (mt << 6)) ^ ((ln & 7) << 4));
                *(uint2*)(Pw + ln * 128 + cbb) = pk.u2;
            }
        rs += __shfl_xor(rs, 32);
        l_i = l_i * fac + rs;

        #pragma unroll
        for (int mt = 0; mt < 2; mt++) {
            floatx16 o = O[mt];
            #pragma unroll
            for (int r = 0; r < 16; r++) o[r] *= fac;
            #pragma unroll
            for (int ks = 0; ks < 4; ks++) {
                int row = mt * 32 + ln;
                int ad  = row * 128 + ((ks * 32 + g * 16) ^ ((row & 7) << 4));
                half8 vf = *(const half8*)(Vts + ad);
                half8 pf = *(const half8*)(Pw + ln * 128 + ((ks * 32 + g * 16) ^ ((ln & 7) << 4)));
                o = __builtin_amdgcn_mfma_f32_32x32x16_f16(vf, pf, o, 0, 0, 0);
            }
            O[mt] = o;
        }
    }

    __syncthreads();
    float inv = 1.f / l_i;
    float* Ot = (float*)lds + w * (64 * 33);
    #pragma unroll
    for (int mt = 0; mt < 2; mt++)
        #pragma unroll
        for (int r = 0; r < 16; r++) {
            int d = (r & 3) + ((r >> 2) << 3) + (g << 2) + (mt << 5);
            Ot[d * 33 + ln] = O[mt][r] * inv;
        }
    #pragma unroll
    for (int ps = 0; ps < 8; ps++) {
        int qrow = ps * 4 + (lane >> 4);
        int dc   = (lane & 15) * 4;
        float4 o;
        o.x = Ot[(dc + 0) * 33 + qrow];
        o.y = Ot[(dc + 1) * 33 + qrow];
        o.z = Ot[(dc + 2) * 33 + qrow];
        o.w = Ot[(dc + 3) * 33 + qrow];
        *(float4*)(out + ((size_t)b * SEQ + q0 + w * 32 + qrow) * DIM + h * HD + dc) = o;
    }
}

extern "C" void kernel_launch(void* const* d_in, const int* in_sizes, int n_in,
                              void* d_out, int out_size, void* d_ws, size_t ws_size,
                              hipStream_t stream) {
    (void)in_sizes; (void)n_in; (void)out_size; (void)ws_size;
    const float* x    = (const float*)d_in[0];
    const float* vels = (const float*)d_in[1];
    const float* Wq   = (const float*)d_in[2];
    const float* bq   = (const float*)d_in[3];
    const float* Wk   = (const float*)d_in[4];
    const float* bk   = (const float*)d_in[5];
    const float* Wv   = (const float*)d_in[6];
    const float* bv   = (const float*)d_in[7];
    float* out = (float*)d_out;

    // ws layout (bytes): biasT 4.19MB | Qh Ql Kh Kl Vt 33.55MB each |
    // WH 6.29MB | WL 6.29MB  -> total 184.5 MB (< 201 MB proven in round 1)
    char* ws = (char*)d_ws;
    const size_t T16 = (size_t)NB * NH * SEQ * HD * 2;   // 33,554,432 B
    float*    biasT = (float*)ws;
    size_t o = 4194304;
    _Float16* Qhp = (_Float16*)(ws + o); o += T16;
    _Float16* Qlp = (_Float16*)(ws + o); o += T16;
    _Float16* Khp = (_Float16*)(ws + o); o += T16;
    _Float16* Klp = (_Float16*)(ws + o); o += T16;
    _Float16* Vtp = (_Float16*)(ws + o); o += T16;
    _Float16* WH  = (_Float16*)(ws + o); o += (size_t)3 * DIM * DIM * 2;
    _Float16* WL  = (_Float16*)(ws + o);

    convw_kernel<<<dim3(DIM * DIM / 1024, 3), 256, 0, stream>>>(Wq, Wk, Wv, WH, WL);
    bias_kernel<<<dim3(SEQ / 256, SEQ), 256, 0, stream>>>(vels, biasT);

    proj_mfma<<<3072, 256, 0, stream>>>(x, WH, WL, bq, bk, bv,
                                        Qhp, Qlp, Khp, Klp, Vtp);

    dim3 agrid(SEQ / 128, NH, NB);
    attn_mfma<<<agrid, 256, 0, stream>>>(Qhp, Qlp, Khp, Klp, Vtp, biasT, out);
}

// Round 6
// 510.871 us; speedup vs baseline: 4.8837x; 1.3293x over previous
//
#include <hip/hip_runtime.h>
#include <math.h>

#define NB 16
#define NH 16
#define SEQ 1024
#define DIM 1024
#define HD 64

typedef _Float16 half8 __attribute__((ext_vector_type(8)));
typedef float floatx16 __attribute__((ext_vector_type(16)));

// async global->LDS, 16B per lane, linear dest (wave-uniform base + lane*16)
#define GLOAD16(gp, lp) __builtin_amdgcn_global_load_lds( \
    (const __attribute__((address_space(1))) void*)(gp),  \
    (__attribute__((address_space(3))) void*)(lp), 16, 0, 0)

// ---------------------------------------------------------------------------
// Kernel 0a: f32 -> f16 conversion (x and the three W matrices).
// ---------------------------------------------------------------------------
__global__ __launch_bounds__(256) void conv_f16(
    const float* __restrict__ src, _Float16* __restrict__ dst, int n)
{
    int i = (blockIdx.x * 256 + threadIdx.x) * 8;
    if (i >= n) return;
    float4 a = *(const float4*)(src + i);
    float4 b = *(const float4*)(src + i + 4);
    union { _Float16 h[8]; uint4 u; } p;
    p.h[0] = (_Float16)a.x; p.h[1] = (_Float16)a.y;
    p.h[2] = (_Float16)a.z; p.h[3] = (_Float16)a.w;
    p.h[4] = (_Float16)b.x; p.h[5] = (_Float16)b.y;
    p.h[6] = (_Float16)b.z; p.h[7] = (_Float16)b.w;
    *(uint4*)(dst + i) = p.u;
}

// ---------------------------------------------------------------------------
// Kernel 0b: transposed positional-bias table biasT[k][q] (f32, S x S).
// log10(1e4)=4 -> div_term[j] = exp(-j/128).
// ---------------------------------------------------------------------------
__global__ void bias_kernel(const float* __restrict__ vels, float* __restrict__ biasT)
{
    int q = blockIdx.x * 256 + threadIdx.x;
    int k = blockIdx.y;
    float ek  = expf(-(float)(k >> 1) * 0.0078125f);
    float ang = vels[q] * ek;
    biasT[(size_t)k * SEQ + q] = (k & 1) ? cosf(ang) : sinf(ang);
}

// ---------------------------------------------------------------------------
// Kernel 1: projections, single-term f16 MFMA.  y = xh @ WH^T + b.
// 128x128 tile, BK=64 (128-B LDS rows, chunk^=row&7 swizzle -> conflict-free
// b128), staging via global_load_lds w/ inverse-swizzled global source.
// XCD-chunked grid: all 24 (n,z) blocks of one m-panel on one XCD.
// z=0 -> Qh, z=1 -> Kh, z=2 -> Vt (B,H,d,s transposed; swapped MFMA).
// ---------------------------------------------------------------------------
__global__ __launch_bounds__(256) void proj_mfma(
    const _Float16* __restrict__ xh, const _Float16* __restrict__ WH,
    const float* __restrict__ bq, const float* __restrict__ bk,
    const float* __restrict__ bvp,
    _Float16* __restrict__ Qh, _Float16* __restrict__ Kh,
    _Float16* __restrict__ Vt)
{
    __shared__ __align__(16) char lds[32768];
    char* Xs = lds;              // [128 m][128 B]
    char* Ws = lds + 16384;      // [128 n][128 B]

    const int t    = threadIdx.x;
    const int lane = t & 63;
    const int w    = t >> 6;
    const int g    = lane >> 5;
    const int ln   = lane & 31;
    const int wm   = w >> 1, wn = w & 1;

    // XCD-chunked decode: xcd = hw%8 (common mapping); same-m panels stay
    // on one XCD, consecutive j iterate (n,z) for temporal reuse.
    const int xcd = blockIdx.x & 7;
    const int j   = blockIdx.x >> 3;          // 0..383
    const int mt_ = (j / 24) * 8 + xcd;       // 0..127
    const int c   = j % 24;
    const int n0  = (c & 7) * 128;
    const int z   = c >> 3;
    const int m0  = mt_ * 128;
    const bool isV = (z == 2);

    const _Float16* Wp = WH + (size_t)z * (DIM * DIM);
    const float* bias = (z == 0) ? bq : (z == 1) ? bk : bvp;

    const int srow = lane >> 3;               // staging row within 8-row group
    const int schk = lane & 7;                // staging 16B chunk

    floatx16 acc[4];
    #pragma unroll
    for (int i = 0; i < 4; i++)
        #pragma unroll
        for (int r = 0; r < 16; r++) acc[i][r] = 0.f;

    for (int k0 = 0; k0 < DIM; k0 += 64) {
        __syncthreads();
        #pragma unroll
        for (int i = 0; i < 4; i++) {
            int r0  = w * 32 + i * 8;
            int row = r0 + srow;
            int cg  = schk ^ (row & 7);       // inverse swizzle on source
            GLOAD16(xh + (size_t)(m0 + row) * DIM + k0 + cg * 8, Xs + r0 * 128);
            GLOAD16(Wp + (size_t)(n0 + row) * DIM + k0 + cg * 8, Ws + r0 * 128);
        }
        __syncthreads();

        #pragma unroll
        for (int ks = 0; ks < 4; ks++) {
            half8 xa[2], wb[2];
            #pragma unroll
            for (int mt = 0; mt < 2; mt++) {
                int row = wm * 64 + mt * 32 + ln;
                xa[mt] = *(const half8*)(Xs + row * 128 + (((ks * 2 + g) ^ (row & 7)) << 4));
            }
            #pragma unroll
            for (int nt = 0; nt < 2; nt++) {
                int row = wn * 64 + nt * 32 + ln;
                wb[nt] = *(const half8*)(Ws + row * 128 + (((ks * 2 + g) ^ (row & 7)) << 4));
            }
            if (!isV) {
                #pragma unroll
                for (int mt = 0; mt < 2; mt++)
                    #pragma unroll
                    for (int nt = 0; nt < 2; nt++)
                        acc[mt * 2 + nt] = __builtin_amdgcn_mfma_f32_32x32x16_f16(
                            xa[mt], wb[nt], acc[mt * 2 + nt], 0, 0, 0);
            } else {
                // swapped so D cols = m (s-contiguous Vt stores)
                #pragma unroll
                for (int nt = 0; nt < 2; nt++)
                    #pragma unroll
                    for (int mt = 0; mt < 2; mt++)
                        acc[nt * 2 + mt] = __builtin_amdgcn_mfma_f32_32x32x16_f16(
                            wb[nt], xa[mt], acc[nt * 2 + mt], 0, 0, 0);
            }
        }
    }

    if (!isV) {
        _Float16* H = (z == 0) ? Qh : Kh;
        float bnv[2];
        #pragma unroll
        for (int nt = 0; nt < 2; nt++) bnv[nt] = bias[n0 + wn * 64 + nt * 32 + ln];
        #pragma unroll
        for (int mt = 0; mt < 2; mt++)
            #pragma unroll
            for (int nt = 0; nt < 2; nt++) {
                int n  = n0 + wn * 64 + nt * 32 + ln;
                int hh = n >> 6, dh = n & 63;
                #pragma unroll
                for (int r = 0; r < 16; r++) {
                    int m = m0 + wm * 64 + mt * 32 + (r & 3) + ((r >> 2) << 3) + (g << 2);
                    float v = acc[mt * 2 + nt][r] + bnv[nt];
                    H[(((size_t)((m >> 10) * NH + hh)) * SEQ + (m & 1023)) * HD + dh] = (_Float16)v;
                }
            }
    } else {
        #pragma unroll
        for (int nt = 0; nt < 2; nt++)
            #pragma unroll
            for (int mt = 0; mt < 2; mt++) {
                int m  = m0 + wm * 64 + mt * 32 + ln;
                int bb = m >> 10, s = m & 1023;
                #pragma unroll
                for (int r = 0; r < 16; r++) {
                    int n = n0 + wn * 64 + nt * 32 + (r & 3) + ((r >> 2) << 3) + (g << 2);
                    float v = acc[nt * 2 + mt][r] + bias[n];
                    Vt[(((size_t)(bb * NH + (n >> 6))) * HD + (n & 63)) * SEQ + s] = (_Float16)v;
                }
            }
    }
}

// ---------------------------------------------------------------------------
// Kernel 2: flash attention, single-term f16 MFMA, swapped operands.
//   QK^T: D[k][q] = mfma(K, Q);  PV: O^T[d][q] = mfma(Vt, P)
// Lane pair (ln, ln+32) owns one q-row; xor-32 joins row max/sum.
// K/V staged via global_load_lds (pre-swizzled source); setprio around MFMA.
// ---------------------------------------------------------------------------
__global__ __launch_bounds__(256) void attn_mfma(
    const _Float16* __restrict__ Qh, const _Float16* __restrict__ Kh,
    const _Float16* __restrict__ Vt, const float* __restrict__ biasT,
    float* __restrict__ out)
{
    __shared__ __align__(16) char lds[33792];
    char* Ks  = lds;                 // 8 KB: K tile [64 kcol][64 d] swz
    char* Vts = lds + 8192;          // 8 KB: Vt tile [64 d][64 s] swz
    // P per-wave: lds + 16384 + w*4096

    const int t    = threadIdx.x;
    const int lane = t & 63;
    const int w    = t >> 6;
    const int g    = lane >> 5;
    const int ln   = lane & 31;
    const int q0   = blockIdx.x * 128;
    const int h = blockIdx.y, b = blockIdx.z;
    const size_t bh = (size_t)b * NH + h;

    const _Float16* Qhp = Qh + bh * (SEQ * HD);
    const _Float16* Khp = Kh + bh * (SEQ * HD);
    const _Float16* Vtp = Vt + bh * (HD * SEQ);
    char* Pw = lds + 16384 + w * 4096;

    const int qr = q0 + w * 32 + ln;
    half8 qf[4];
    #pragma unroll
    for (int ks = 0; ks < 4; ks++)
        qf[ks] = *(const half8*)(Qhp + (size_t)qr * HD + ks * 16 + g * 8);

    floatx16 O[2];
    #pragma unroll
    for (int mt = 0; mt < 2; mt++)
        #pragma unroll
        for (int r = 0; r < 16; r++) O[mt][r] = 0.f;
    float m_i = -1e30f, l_i = 0.f;

    const int srow = lane >> 3;
    const int schk = lane & 7;

    for (int kt = 0; kt < SEQ; kt += 64) {
        __syncthreads();
        #pragma unroll
        for (int i = 0; i < 2; i++) {
            int r0  = w * 16 + i * 8;
            int row = r0 + srow;
            int cg  = schk ^ (row & 7);
            GLOAD16(Khp + (size_t)(kt + row) * HD + cg * 8, Ks + r0 * 128);
            GLOAD16(Vtp + (size_t)row * SEQ + kt + cg * 8, Vts + r0 * 128);
        }
        __syncthreads();

        // ---- QK^T
        float sc[2][16];
        __builtin_amdgcn_s_setprio(1);
        #pragma unroll
        for (int mt = 0; mt < 2; mt++) {
            floatx16 acc;
            #pragma unroll
            for (int r = 0; r < 16; r++) acc[r] = 0.f;
            #pragma unroll
            for (int ks = 0; ks < 4; ks++) {
                int row = mt * 32 + ln;
                half8 kh = *(const half8*)(Ks + row * 128 + (((ks * 2 + g) ^ (row & 7)) << 4));
                acc = __builtin_amdgcn_mfma_f32_32x32x16_f16(kh, qf[ks], acc, 0, 0, 0);
            }
            #pragma unroll
            for (int r = 0; r < 16; r++) sc[mt][r] = acc[r];
        }
        __builtin_amdgcn_s_setprio(0);

        // ---- bias + online softmax (row split across lane pair; xor-32 joins)
        const float* bT = biasT + (size_t)kt * SEQ + q0 + w * 32 + ln;
        float mx = m_i;
        #pragma unroll
        for (int mt = 0; mt < 2; mt++)
            #pragma unroll
            for (int r = 0; r < 16; r++) {
                int kc = (r & 3) + ((r >> 2) << 3) + (g << 2) + (mt << 5);
                float v = fmaf(sc[mt][r], 0.125f, bT[(size_t)kc * SEQ]);
                sc[mt][r] = v;
                mx = fmaxf(mx, v);
            }
        mx = fmaxf(mx, __shfl_xor(mx, 32));
        float fac = __expf(m_i - mx);
        m_i = mx;
        float rs = 0.f;
        #pragma unroll
        for (int mt = 0; mt < 2; mt++)
            #pragma unroll
            for (int rb = 0; rb < 4; rb++) {
                float p0 = __expf(sc[mt][rb * 4 + 0] - mx);
                float p1 = __expf(sc[mt][rb * 4 + 1] - mx);
                float p2 = __expf(sc[mt][rb * 4 + 2] - mx);
                float p3 = __expf(sc[mt][rb * 4 + 3] - mx);
                rs += (p0 + p1) + (p2 + p3);
                union { _Float16 hv[4]; uint2 u2; } pk;
                pk.hv[0] = (_Float16)p0; pk.hv[1] = (_Float16)p1;
                pk.hv[2] = (_Float16)p2; pk.hv[3] = (_Float16)p3;
                int cbb = (((rb << 4) + (g << 3) + (mt << 6)) ^ ((ln & 7) << 4));
                *(uint2*)(Pw + ln * 128 + cbb) = pk.u2;
            }
        rs += __shfl_xor(rs, 32);
        l_i = l_i * fac + rs;

        // ---- PV
        __builtin_amdgcn_s_setprio(1);
        #pragma unroll
        for (int mt = 0; mt < 2; mt++) {
            floatx16 o = O[mt];
            #pragma unroll
            for (int r = 0; r < 16; r++) o[r] *= fac;
            #pragma unroll
            for (int ks = 0; ks < 4; ks++) {
                int row = mt * 32 + ln;
                half8 vf = *(const half8*)(Vts + row * 128 + (((ks * 2 + g) ^ (row & 7)) << 4));
                half8 pf = *(const half8*)(Pw + ln * 128 + ((ks * 32 + g * 16) ^ ((ln & 7) << 4)));
                o = __builtin_amdgcn_mfma_f32_32x32x16_f16(vf, pf, o, 0, 0, 0);
            }
            O[mt] = o;
        }
        __builtin_amdgcn_s_setprio(0);
    }

    // ---- epilogue: O^T -> LDS transpose -> coalesced f32 stores
    __syncthreads();
    float inv = 1.f / l_i;
    float* Ot = (float*)lds + w * (64 * 33);
    #pragma unroll
    for (int mt = 0; mt < 2; mt++)
        #pragma unroll
        for (int r = 0; r < 16; r++) {
            int d = (r & 3) + ((r >> 2) << 3) + (g << 2) + (mt << 5);
            Ot[d * 33 + ln] = O[mt][r] * inv;
        }
    #pragma unroll
    for (int ps = 0; ps < 8; ps++) {
        int qrow = ps * 4 + (lane >> 4);
        int dc   = (lane & 15) * 4;
        float4 o;
        o.x = Ot[(dc + 0) * 33 + qrow];
        o.y = Ot[(dc + 1) * 33 + qrow];
        o.z = Ot[(dc + 2) * 33 + qrow];
        o.w = Ot[(dc + 3) * 33 + qrow];
        *(float4*)(out + ((size_t)b * SEQ + q0 + w * 32 + qrow) * DIM + h * HD + dc) = o;
    }
}

extern "C" void kernel_launch(void* const* d_in, const int* in_sizes, int n_in,
                              void* d_out, int out_size, void* d_ws, size_t ws_size,
                              hipStream_t stream) {
    (void)in_sizes; (void)n_in; (void)out_size; (void)ws_size;
    const float* x    = (const float*)d_in[0];
    const float* vels = (const float*)d_in[1];
    const float* Wq   = (const float*)d_in[2];
    const float* bq   = (const float*)d_in[3];
    const float* Wk   = (const float*)d_in[4];
    const float* bk   = (const float*)d_in[5];
    const float* Wv   = (const float*)d_in[6];
    const float* bv   = (const float*)d_in[7];
    float* out = (float*)d_out;

    // ws layout (bytes): biasT 4.19MB | xh 33.55 | Qh 33.55 | Kh 33.55 |
    // Vt 33.55 | WH 6.29  -> ~144.7 MB
    char* ws = (char*)d_ws;
    const size_t T16 = (size_t)NB * SEQ * DIM * 2;       // 33,554,432 B
    float*    biasT = (float*)ws;
    size_t o = 4194304;
    _Float16* xh  = (_Float16*)(ws + o); o += T16;
    _Float16* Qhp = (_Float16*)(ws + o); o += T16;
    _Float16* Khp = (_Float16*)(ws + o); o += T16;
    _Float16* Vtp = (_Float16*)(ws + o); o += T16;
    _Float16* WH  = (_Float16*)(ws + o);

    conv_f16<<<8192, 256, 0, stream>>>(x, xh, NB * SEQ * DIM);
    conv_f16<<<512, 256, 0, stream>>>(Wq, WH, DIM * DIM);
    conv_f16<<<512, 256, 0, stream>>>(Wk, WH + (size_t)DIM * DIM, DIM * DIM);
    conv_f16<<<512, 256, 0, stream>>>(Wv, WH + (size_t)2 * DIM * DIM, DIM * DIM);
    bias_kernel<<<dim3(SEQ / 256, SEQ), 256, 0, stream>>>(vels, biasT);

    proj_mfma<<<3072, 256, 0, stream>>>(xh, WH, bq, bk, bv, Qhp, Khp, Vtp);

    dim3 agrid(SEQ / 128, NH, NB);
    attn_mfma<<<agrid, 256, 0, stream>>>(Qhp, Khp, Vtp, biasT, out);
}